// Round 1
// 437.423 us; speedup vs baseline: 1.1365x; 1.1365x over previous
//
#include <hip/hip_runtime.h>
#include <math.h>

#define BB 8
#define TT 200
#define UU 100
#define U1 101
#define VV 512
#define PS 102                      // padded row stride (floats), 8B-aligned float2 lanes
#define ND 320                      // diagonal rows per batch: T+U1-1=300, padded to let
                                    // the PF-deep pipeline overrun into poison rows safely
#define PF 8                        // load-pipeline depth (must keep indices compile-time)
#define NEG_BIG (-1.0e30f)          // lae identity; finite so no NaN (-inf - -inf) path
#define L2E 1.4426950408889634f
#define LN2 0.6931471805599453f

// v_exp_f32 is natively 2^x; HIP has no __exp2f fast intrinsic (glibc macro clash)
__device__ __forceinline__ float exp2_fast(float x) { return __builtin_amdgcn_exp2f(x); }

// ---------------------------------------------------------------------------
// DPP helper: dst = dpp_move(src) per CTRL; lanes not written (row-mask or
// out-of-bounds with bound_ctrl=false) yield `old`.
// ---------------------------------------------------------------------------
template<int CTRL, int RM>
__device__ __forceinline__ float dppf(float old, float x) {
    return __int_as_float(__builtin_amdgcn_update_dpp(
        __float_as_int(old), __float_as_int(x), CTRL, RM, 0xF, false));
}

// base-2 logaddexp; finite-in -> finite-out (no NaN), exact when |d| large
__device__ __forceinline__ float lae2(float x, float y) {
    float d = x - y;
    float e = exp2_fast(-fabsf(d));
    return fmaxf(x, y) + __log2f(1.0f + e);
}

// whole-wave shift right by 1 (E[i] = x[i-1], E[0] = ident): row_shr:1 plus
// row_bcast fixups for the three row boundaries, selected by precomputed masks.
__device__ __forceinline__ float wave_shr1(float x, bool c1648, bool c32) {
    float t   = dppf<0x111, 0xF>(NEG_BIG, x);   // lanes 0,16,32,48 -> ident
    float b15 = dppf<0x142, 0xA>(NEG_BIG, x);   // 16-31 := x[15], 48-63 := x[47]
    float b31 = dppf<0x143, 0x4>(NEG_BIG, x);   // 32-47 := x[31]
    float e = c1648 ? b15 : t;
    return c32 ? b31 : e;
}

// ---------------------------------------------------------------------------
// Kernel 1: per-row log-softmax over V=512, one wave per (b,t,u) row.
// Skips rows never read by the recursion (t >= Tb or u > Ub): ~43% less HBM.
// Writes base-2 log-probs in DIAGONAL-MAJOR layout: slot [b][t+u][u], so the
// alpha kernel's per-diagonal reads are coalesced float2 rows. Skipped slots
// stay 0xAA-poison (finite, ~-3e-13) and provably only contaminate lattice
// cells with t >= Tb or u > Ub, which the causal (t-1, u-1) recursion never
// propagates into the read cell (Tb-1, Ub).
// ---------------------------------------------------------------------------
__global__ __launch_bounds__(256) void row_lse_kernel(
    const float* __restrict__ acts, const int* __restrict__ labels,
    const int* __restrict__ act_lens, const int* __restrict__ label_lens,
    float* __restrict__ blank_lp, float* __restrict__ emit_lp)
{
    const int wave = (blockIdx.x << 2) | ((int)threadIdx.x >> 6);
    const int lane = threadIdx.x & 63;
    if (wave >= BB * TT * U1) return;

    const int u  = wave % U1;
    const int bt = wave / U1;     // b*TT + t
    const int b  = bt / TT;
    const int t  = bt % TT;
    const int Ub = label_lens[b];
    if (t >= act_lens[b] || u > Ub) return;   // dead lattice row

    const float* row = acts + (size_t)wave * VV;
    float4 a = ((const float4*)row)[lane];
    float4 c = ((const float4*)row)[lane + 64];

    float m = fmaxf(fmaxf(fmaxf(a.x, a.y), fmaxf(a.z, a.w)),
                    fmaxf(fmaxf(c.x, c.y), fmaxf(c.z, c.w)));
    #pragma unroll
    for (int off = 32; off; off >>= 1)
        m = fmaxf(m, __shfl_xor(m, off, 64));

    float s = __expf(a.x - m) + __expf(a.y - m) + __expf(a.z - m) + __expf(a.w - m)
            + __expf(c.x - m) + __expf(c.y - m) + __expf(c.z - m) + __expf(c.w - m);
    #pragma unroll
    for (int off = 32; off; off >>= 1)
        s += __shfl_xor(s, off, 64);

    const float denom = m + __logf(s);

    // diagonal-major slot for cell (t, u)
    const int dn = (b * ND + t + u) * PS + u;

    float x0 = __shfl(a.x, 0, 64);            // blank logit = x[0]
    if (lane == 0) blank_lp[dn] = (x0 - denom) * L2E;

    if (u < UU) {
        int lbl = labels[b * UU + u];         // wave-uniform
        int e   = lbl & 3;
        int src = (lbl >> 2) & 63;
        float4 s4 = (lbl < 256) ? a : c;
        float cand = (e == 0) ? s4.x : (e == 1) ? s4.y : (e == 2) ? s4.z : s4.w;
        float xl = __shfl(cand, src, 64);
        if (lane == 0) emit_lp[dn] = (xl - denom) * L2E;
    }
}

// ---------------------------------------------------------------------------
// Kernel 2: anti-diagonal wavefront alpha recursion, one wave per batch
// element, all in base-2 logs. Lane i owns u = 2i, 2i+1; A[n][u] is alpha at
// lattice cell (t = n-u, u):
//   A[n][u] = lae2( A[n-1][u] + bl_d[n-1][u],  A[n-1][u-1] + em_d[n-1][u-1] )
// Critical path per diagonal = one add + one DPP shift + one lae2 (~35 cyc),
// vs the old row-scan's 8-deep lae2 chain (~260 cyc) per t-row.
// Loads (rows n-1 of bl_d/em_d) depend only on n, so an 8-deep unrolled
// register pipeline (static indices -> no scratch) covers L2 latency.
// Never-written diagonal slots hold finite 0xAA poison; cells contaminated by
// them (t >= Tb or u > Ub) are never on the causal path to (Tb-1, Ub).
// ---------------------------------------------------------------------------
__global__ __launch_bounds__(64) void alpha_kernel(
    const float* __restrict__ blank_lp, const float* __restrict__ emit_lp,
    const int* __restrict__ act_lens, const int* __restrict__ label_lens,
    float* __restrict__ out)
{
    const int b    = blockIdx.x;
    const int lane = threadIdx.x;
    const float* bl = blank_lp + (size_t)b * ND * PS;
    const float* em = emit_lp  + (size_t)b * ND * PS;
    const int Tb = act_lens[b];
    const int Ub = label_lens[b];
    const int nfin = Tb - 1 + Ub;             // diagonal holding cell (Tb-1, Ub)

    const int  ll    = (lane < 50) ? lane : 50;   // lanes >50 dup lane 50 (harmless)
    const bool c1648 = (lane == 16) || (lane == 48);
    const bool c32   = (lane == 32);

    const float blfin = bl[nfin * PS + Ub];   // bl_d[Tb-1+Ub][Ub] = bl[Tb-1][Ub]

    auto load2 = [&](const float* base, int row) -> float2 {
        return ((const float2*)(base + row * PS))[ll];
    };

    // prime the PF-deep register pipeline with diagonal rows 0..PF-1
    float2 blb[PF], emb[PF];
    #pragma unroll
    for (int k = 0; k < PF; ++k) {
        blb[k] = load2(bl, k);
        emb[k] = load2(em, k);
    }

    // diagonal 0: only cell (0,0) = 0
    float a0 = (lane == 0) ? 0.0f : NEG_BIG;
    float a1 = NEG_BIG;
    float rcap = NEG_BIG;

    // n0 blocks of PF diagonals; last block may overrun past nfin into poison
    // rows (finite garbage, computed after the capture -> harmless). Max row
    // touched by refill: nfin-1+2*PF <= 298+16 = 314 < ND=320, in-bounds.
    for (int n0 = 1; n0 <= nfin; n0 += PF) {
        #pragma unroll
        for (int k = 0; k < PF; ++k) {
            const int n = n0 + k;
            // row n-1 of both arrays is in slot k
            float b0  = a0 + blb[k].x;        // t-term, u = 2*lane
            float b1  = a1 + blb[k].y;        // t-term, u = 2*lane+1
            float ein = a0 + emb[k].x;        // u-term for new a1 (in-lane)
            float y   = a1 + emb[k].y;        // u-term source for lane+1's a0
            float esh = wave_shr1(y, c1648, c32);
            a0 = lae2(b0, esh);
            a1 = lae2(b1, ein);
            if (n == nfin) rcap = (Ub & 1) ? a1 : a0;   // wave-uniform scalar cmp
            // refill slot k with diagonal row (n-1)+PF for PF steps from now
            const int nr = n - 1 + PF;
            blb[k] = load2(bl, nr);
            emb[k] = load2(em, nr);
        }
    }

    float res = __shfl(rcap, Ub >> 1, 64);
    if (lane == 0)
        atomicAdd(out, -(res + blfin) * LN2);
}

extern "C" void kernel_launch(void* const* d_in, const int* in_sizes, int n_in,
                              void* d_out, int out_size, void* d_ws, size_t ws_size,
                              hipStream_t stream) {
    const float* acts       = (const float*)d_in[0];
    const int*   labels     = (const int*)d_in[1];
    const int*   act_lens   = (const int*)d_in[2];
    const int*   label_lens = (const int*)d_in[3];
    float* out = (float*)d_out;

    float* blank_lp = (float*)d_ws;                 // B*ND*PS floats (diag-major)
    float* emit_lp  = blank_lp + BB * ND * PS;      // B*ND*PS floats

    const int nrows   = BB * TT * U1;               // 161600
    const int blocks1 = (nrows + 3) / 4;            // 4 waves/block

    (void)hipMemsetAsync(d_out, 0, (size_t)out_size * sizeof(float), stream);
    row_lse_kernel<<<blocks1, 256, 0, stream>>>(acts, labels, act_lens, label_lens,
                                                blank_lp, emit_lp);
    alpha_kernel<<<BB, 64, 0, stream>>>(blank_lp, emit_lp, act_lens, label_lens, out);
}

// Round 3
// 425.160 us; speedup vs baseline: 1.1693x; 1.0288x over previous
//
#include <hip/hip_runtime.h>
#include <math.h>

#define BB 8
#define TT 200
#define UU 100
#define U1 101
#define VV 512
#define NP 51                       // u-row pairs per (b,t): ceil(U1/2)
#define PS 102                      // padded row stride (floats), 8B-aligned float2 lanes
#define ND 320                      // diagonal rows per batch: T+U1-1=300, padded to let
                                    // the PF-deep pipeline overrun into poison rows safely
#define PF 8                        // load-pipeline depth (must keep indices compile-time)
#define NEG_BIG (-1.0e30f)          // lae identity; finite so no NaN (-inf - -inf) path
#define L2E 1.4426950408889634f
#define LN2 0.6931471805599453f

typedef float f32x4 __attribute__((ext_vector_type(4)));  // clang vector: OK for
                                                          // __builtin_nontemporal_load

// v_exp_f32 is natively 2^x; HIP has no __exp2f fast intrinsic (glibc macro clash)
__device__ __forceinline__ float exp2_fast(float x) { return __builtin_amdgcn_exp2f(x); }

// ---------------------------------------------------------------------------
// DPP helper: dst = dpp_move(src) per CTRL; lanes not written (row-mask or
// out-of-bounds with bound_ctrl=false) yield `old`.
// ---------------------------------------------------------------------------
template<int CTRL, int RM>
__device__ __forceinline__ float dppf(float old, float x) {
    return __int_as_float(__builtin_amdgcn_update_dpp(
        __float_as_int(old), __float_as_int(x), CTRL, RM, 0xF, false));
}

// base-2 logaddexp; finite-in -> finite-out (no NaN), exact when |d| large
__device__ __forceinline__ float lae2(float x, float y) {
    float d = x - y;
    float e = exp2_fast(-fabsf(d));
    return fmaxf(x, y) + __log2f(1.0f + e);
}

// whole-wave shift right by 1 (E[i] = x[i-1], E[0] = ident): row_shr:1 plus
// row_bcast fixups for the three row boundaries, selected by precomputed masks.
__device__ __forceinline__ float wave_shr1(float x, bool c1648, bool c32) {
    float t   = dppf<0x111, 0xF>(NEG_BIG, x);   // lanes 0,16,32,48 -> ident
    float b15 = dppf<0x142, 0xA>(NEG_BIG, x);   // 16-31 := x[15], 48-63 := x[47]
    float b31 = dppf<0x143, 0x4>(NEG_BIG, x);   // 32-47 := x[31]
    float e = c1648 ? b15 : t;
    return c32 ? b31 : e;
}

// ---------------------------------------------------------------------------
// Kernel 1: per-row log-softmax over V=512, one wave per PAIR of u-rows of a
// (b,t) slab. Two rows/wave = 4 independent float4 (nt) loads issued up front
// and two independent reduction chains -> 2x the memory-level and ALU ILP of
// the one-row version (which measured ~3.3 TB/s effective; this targets ~5+).
// Skips rows never read by the recursion (t >= Tb or u > Ub): ~43% less HBM.
// Writes base-2 log-probs in DIAGONAL-MAJOR layout: slot [b][t+u][u], so the
// alpha kernel's per-diagonal reads are coalesced float2 rows. Skipped slots
// stay 0xAA-poison (finite, ~-3e-13) and provably only contaminate lattice
// cells with t >= Tb or u > Ub, which the causal (t-1, u-1) recursion never
// propagates into the read cell (Tb-1, Ub).
// ---------------------------------------------------------------------------
__global__ __launch_bounds__(256) void row_lse_kernel(
    const float* __restrict__ acts, const int* __restrict__ labels,
    const int* __restrict__ act_lens, const int* __restrict__ label_lens,
    float* __restrict__ blank_lp, float* __restrict__ emit_lp)
{
    const int wave = (blockIdx.x << 2) | ((int)threadIdx.x >> 6);
    const int lane = threadIdx.x & 63;
    if (wave >= BB * TT * NP) return;

    const int pr = wave % NP;
    const int bt = wave / NP;     // b*TT + t
    const int b  = bt / TT;
    const int t  = bt % TT;
    const int u0 = pr * 2;
    const int u1 = u0 + 1;
    const int Ub = label_lens[b];
    if (t >= act_lens[b] || u0 > Ub) return;     // u0 dead => u1 dead too

    const bool live1 = (u1 < U1) && (u1 <= Ub);

    const f32x4* r0 = (const f32x4*)(acts + ((size_t)(bt * U1) + u0) * VV);
    f32x4 a = __builtin_nontemporal_load(r0 + lane);
    f32x4 c = __builtin_nontemporal_load(r0 + lane + 64);
    f32x4 e, g;
    if (live1) {
        const f32x4* r1 = r0 + 128;              // next u-row, contiguous
        e = __builtin_nontemporal_load(r1 + lane);
        g = __builtin_nontemporal_load(r1 + lane + 64);
    } else { e = a; g = c; }                     // dup row0: single code path

    float m0 = fmaxf(fmaxf(fmaxf(a.x, a.y), fmaxf(a.z, a.w)),
                     fmaxf(fmaxf(c.x, c.y), fmaxf(c.z, c.w)));
    float m1 = fmaxf(fmaxf(fmaxf(e.x, e.y), fmaxf(e.z, e.w)),
                     fmaxf(fmaxf(g.x, g.y), fmaxf(g.z, g.w)));
    #pragma unroll
    for (int off = 32; off; off >>= 1) {
        m0 = fmaxf(m0, __shfl_xor(m0, off, 64));
        m1 = fmaxf(m1, __shfl_xor(m1, off, 64));
    }

    float s0 = __expf(a.x - m0) + __expf(a.y - m0) + __expf(a.z - m0) + __expf(a.w - m0)
             + __expf(c.x - m0) + __expf(c.y - m0) + __expf(c.z - m0) + __expf(c.w - m0);
    float s1 = __expf(e.x - m1) + __expf(e.y - m1) + __expf(e.z - m1) + __expf(e.w - m1)
             + __expf(g.x - m1) + __expf(g.y - m1) + __expf(g.z - m1) + __expf(g.w - m1);
    #pragma unroll
    for (int off = 32; off; off >>= 1) {
        s0 += __shfl_xor(s0, off, 64);
        s1 += __shfl_xor(s1, off, 64);
    }

    const float den0 = m0 + __logf(s0);
    const float den1 = m1 + __logf(s1);

    // diagonal-major slots for cells (t, u0) and (t, u1)
    const int dn0 = (b * ND + t + u0) * PS + u0;
    const int dn1 = (b * ND + t + u1) * PS + u1;

    float x0 = __shfl(a.x, 0, 64);               // blank logit = row[0]
    float x1 = __shfl(e.x, 0, 64);
    if (lane == 0) {
        blank_lp[dn0] = (x0 - den0) * L2E;
        if (live1) blank_lp[dn1] = (x1 - den1) * L2E;
    }

    {   // emit for u0 (u0 <= 99 guaranteed when u0 < UU)
        if (u0 < UU) {
            int lbl = labels[b * UU + u0];       // wave-uniform
            int el  = lbl & 3;
            int src = (lbl >> 2) & 63;
            f32x4 s4 = (lbl < 256) ? a : c;
            float cand = (el == 0) ? s4.x : (el == 1) ? s4.y : (el == 2) ? s4.z : s4.w;
            float xl = __shfl(cand, src, 64);
            if (lane == 0) emit_lp[dn0] = (xl - den0) * L2E;
        }
        if (live1 && u1 < UU) {
            int lbl = labels[b * UU + u1];
            int el  = lbl & 3;
            int src = (lbl >> 2) & 63;
            f32x4 s4 = (lbl < 256) ? e : g;
            float cand = (el == 0) ? s4.x : (el == 1) ? s4.y : (el == 2) ? s4.z : s4.w;
            float xl = __shfl(cand, src, 64);
            if (lane == 0) emit_lp[dn1] = (xl - den1) * L2E;
        }
    }
}

// ---------------------------------------------------------------------------
// Kernel 2: anti-diagonal wavefront alpha recursion, one wave per batch
// element, all in base-2 logs. Lane i owns u = 2i, 2i+1; A[n][u] is alpha at
// lattice cell (t = n-u, u):
//   A[n][u] = lae2( A[n-1][u] + bl_d[n-1][u],  A[n-1][u-1] + em_d[n-1][u-1] )
// Critical path per diagonal = one add + one DPP shift + one lae2 (~35 cyc),
// vs the old row-scan's 8-deep lae2 chain (~260 cyc) per t-row.
// Loads (rows n-1 of bl_d/em_d) depend only on n, so an 8-deep unrolled
// register pipeline (static indices -> no scratch) covers L2 latency.
// Never-written diagonal slots hold finite 0xAA poison; cells contaminated by
// them (t >= Tb or u > Ub) are never on the causal path to (Tb-1, Ub).
// ---------------------------------------------------------------------------
__global__ __launch_bounds__(64) void alpha_kernel(
    const float* __restrict__ blank_lp, const float* __restrict__ emit_lp,
    const int* __restrict__ act_lens, const int* __restrict__ label_lens,
    float* __restrict__ out)
{
    const int b    = blockIdx.x;
    const int lane = threadIdx.x;
    const float* bl = blank_lp + (size_t)b * ND * PS;
    const float* em = emit_lp  + (size_t)b * ND * PS;
    const int Tb = act_lens[b];
    const int Ub = label_lens[b];
    const int nfin = Tb - 1 + Ub;             // diagonal holding cell (Tb-1, Ub)

    const int  ll    = (lane < 50) ? lane : 50;   // lanes >50 dup lane 50 (harmless)
    const bool c1648 = (lane == 16) || (lane == 48);
    const bool c32   = (lane == 32);

    const float blfin = bl[nfin * PS + Ub];   // bl_d[Tb-1+Ub][Ub] = bl[Tb-1][Ub]

    auto load2 = [&](const float* base, int row) -> float2 {
        return ((const float2*)(base + row * PS))[ll];
    };

    // prime the PF-deep register pipeline with diagonal rows 0..PF-1
    float2 blb[PF], emb[PF];
    #pragma unroll
    for (int k = 0; k < PF; ++k) {
        blb[k] = load2(bl, k);
        emb[k] = load2(em, k);
    }

    // diagonal 0: only cell (0,0) = 0
    float a0 = (lane == 0) ? 0.0f : NEG_BIG;
    float a1 = NEG_BIG;
    float rcap = NEG_BIG;

    // n0 blocks of PF diagonals; last block may overrun past nfin into poison
    // rows (finite garbage, computed after the capture -> harmless). Max row
    // touched by refill: nfin-1+2*PF <= 298+16 = 314 < ND=320, in-bounds.
    for (int n0 = 1; n0 <= nfin; n0 += PF) {
        #pragma unroll
        for (int k = 0; k < PF; ++k) {
            const int n = n0 + k;
            // row n-1 of both arrays is in slot k
            float b0  = a0 + blb[k].x;        // t-term, u = 2*lane
            float b1  = a1 + blb[k].y;        // t-term, u = 2*lane+1
            float ein = a0 + emb[k].x;        // u-term for new a1 (in-lane)
            float y   = a1 + emb[k].y;        // u-term source for lane+1's a0
            float esh = wave_shr1(y, c1648, c32);
            a0 = lae2(b0, esh);
            a1 = lae2(b1, ein);
            if (n == nfin) rcap = (Ub & 1) ? a1 : a0;   // wave-uniform scalar cmp
            // refill slot k with diagonal row (n-1)+PF for PF steps from now
            const int nr = n - 1 + PF;
            blb[k] = load2(bl, nr);
            emb[k] = load2(em, nr);
        }
    }

    float res = __shfl(rcap, Ub >> 1, 64);
    if (lane == 0)
        atomicAdd(out, -(res + blfin) * LN2);
}

extern "C" void kernel_launch(void* const* d_in, const int* in_sizes, int n_in,
                              void* d_out, int out_size, void* d_ws, size_t ws_size,
                              hipStream_t stream) {
    const float* acts       = (const float*)d_in[0];
    const int*   labels     = (const int*)d_in[1];
    const int*   act_lens   = (const int*)d_in[2];
    const int*   label_lens = (const int*)d_in[3];
    float* out = (float*)d_out;

    float* blank_lp = (float*)d_ws;                 // B*ND*PS floats (diag-major)
    float* emit_lp  = blank_lp + BB * ND * PS;      // B*ND*PS floats

    const int npairs  = BB * TT * NP;               // 81600 waves
    const int blocks1 = (npairs + 3) / 4;           // 4 waves/block

    (void)hipMemsetAsync(d_out, 0, (size_t)out_size * sizeof(float), stream);
    row_lse_kernel<<<blocks1, 256, 0, stream>>>(acts, labels, act_lens, label_lens,
                                                blank_lp, emit_lp);
    alpha_kernel<<<BB, 64, 0, stream>>>(blank_lp, emit_lp, act_lens, label_lens, out);
}